// Round 1
// baseline (1002.259 us; speedup 1.0000x reference)
//
#include <hip/hip_runtime.h>
#include <stdint.h>

// ---------------- common types / helpers ----------------

typedef short bf16x8 __attribute__((ext_vector_type(8)));
typedef float f32x4 __attribute__((ext_vector_type(4)));

struct alignas(8) us4 { unsigned short x, y, z, w; };

__device__ __forceinline__ unsigned short f32_to_bf16(float f) {
  union { float f; uint32_t u; } v; v.f = f;
  uint32_t u = v.u;
  uint32_t r = (u + 0x7fffu + ((u >> 16) & 1u)) >> 16;  // RNE
  return (unsigned short)r;
}

__device__ __forceinline__ float bf16_to_f32(unsigned short h) {
  union { uint32_t u; float f; } v; v.u = ((uint32_t)h) << 16;
  return v.f;
}

// async global->LDS, 16B per lane; LDS dest is wave-uniform base + lane*16
__device__ __forceinline__ void g2l16(const unsigned short* g, unsigned short* l) {
  __builtin_amdgcn_global_load_lds((__attribute__((address_space(1))) void*)g,
                                   (__attribute__((address_space(3))) void*)l,
                                   16, 0, 0);
}

// ---------------- problem constants ----------------
// B=128, S=512, D=768, NH=8, HD=96, HID=384
// M = B*S = 65536, K = D = 768, N = NH*HD = 768

#define N_X   50331648   // 128*512*768
#define N_P   589824     // 8*96*768
#define N_W1  294912     // 8*384*96
#define N_W2  294912     // 8*96*384
#define N_HI  50331648   // 8*128*512*96

// ---------------- kernel 0: fp32 -> bf16 cast ----------------

__global__ __launch_bounds__(256) void cast_f32_bf16(
    const float* __restrict__ src, unsigned short* __restrict__ dst, int n4) {
  int idx = blockIdx.x * 256 + threadIdx.x;
  if (idx >= n4) return;
  float4 v = ((const float4*)src)[idx];
  us4 o;
  o.x = f32_to_bf16(v.x);
  o.y = f32_to_bf16(v.y);
  o.z = f32_to_bf16(v.z);
  o.w = f32_to_bf16(v.w);
  ((us4*)dst)[idx] = o;
}

// ---------------- kernel 1: Hi = X @ P^T + bP ----------------
// X: (65536 x 768) bf16 row-major. P: (768 x 768) bf16 row-major = B^T layout.
// Output Hi bf16 in (i, b, s, h) layout: [((i*128+b)*512+s)*96 + h].
// 128x128 block tile, BK=32, 256 threads = 4 waves, each wave 4x4 16x16 tiles.

__global__ __launch_bounds__(256) void gemm_hi(
    const unsigned short* __restrict__ Xbf,
    const unsigned short* __restrict__ Pbf,
    const float* __restrict__ bP,
    unsigned short* __restrict__ Hi) {
  __shared__ __align__(16) unsigned short As[128 * 32];
  __shared__ __align__(16) unsigned short Bs[128 * 32];

  const int tid = threadIdx.x;
  const int w = tid >> 6;
  const int lane = tid & 63;
  const int r = lane & 15;
  const int q = lane >> 4;
  const int bn = blockIdx.x;  // 0..5
  const int bm = blockIdx.y;  // 0..511
  const int wr = w >> 1, wc = w & 1;

  f32x4 acc[4][4];
#pragma unroll
  for (int a = 0; a < 4; ++a)
#pragma unroll
    for (int c = 0; c < 4; ++c) acc[a][c] = (f32x4){0.f, 0.f, 0.f, 0.f};

  const int ldr = lane >> 2;       // row within 16-row segment
  const int ldc = (lane & 3) * 8;  // element col offset (16B chunks)
  const unsigned short* Abase = Xbf + (size_t)(bm * 128) * 768 + ldc;
  const unsigned short* Bbase = Pbf + (size_t)(bn * 128) * 768 + ldc;

  for (int k0 = 0; k0 < 768; k0 += 32) {
    __syncthreads();  // previous tile consumed
    g2l16(Abase + (size_t)(w * 16 + ldr) * 768 + k0, &As[w * 512]);
    g2l16(Abase + (size_t)(64 + w * 16 + ldr) * 768 + k0, &As[(4 + w) * 512]);
    g2l16(Bbase + (size_t)(w * 16 + ldr) * 768 + k0, &Bs[w * 512]);
    g2l16(Bbase + (size_t)(64 + w * 16 + ldr) * 768 + k0, &Bs[(4 + w) * 512]);
    __syncthreads();  // drains vmcnt (compiler emits waitcnt before s_barrier)

    bf16x8 af[4], bfr[4];
#pragma unroll
    for (int t = 0; t < 4; ++t)
      af[t] = *(const bf16x8*)&As[(wr * 64 + t * 16 + r) * 32 + q * 8];
#pragma unroll
    for (int t = 0; t < 4; ++t)
      bfr[t] = *(const bf16x8*)&Bs[(wc * 64 + t * 16 + r) * 32 + q * 8];
#pragma unroll
    for (int mt = 0; mt < 4; ++mt)
#pragma unroll
      for (int nt = 0; nt < 4; ++nt)
        acc[mt][nt] = __builtin_amdgcn_mfma_f32_16x16x32_bf16(
            af[mt], bfr[nt], acc[mt][nt], 0, 0, 0);
  }

  // epilogue: C/D layout col = lane&15, row = q*4 + reg (m89/m91-verified)
  const int bb = bm >> 2;                    // batch (512/128 = 4 blocks per batch)
  const int sb = (bm & 3) * 128 + wr * 64;   // s base
#pragma unroll
  for (int nt = 0; nt < 4; ++nt) {
    const int n0 = bn * 128 + wc * 64 + nt * 16;  // multiple of 16; never straddles head (96 = 6*16)
    const int hd = n0 / 96;
    const int h = n0 - hd * 96 + r;
    const float bias = bP[n0 + r];
    unsigned short* obase = Hi + (size_t)(hd * 128 + bb) * 512 * 96 + h;
#pragma unroll
    for (int mt = 0; mt < 4; ++mt) {
#pragma unroll
      for (int rg = 0; rg < 4; ++rg) {
        const int s = sb + mt * 16 + q * 4 + rg;
        obase[(size_t)s * 96] = f32_to_bf16(acc[mt][nt][rg] + bias);
      }
    }
  }
}

// ---------------- kernel 2: fused per-head MLP -> logits ----------------
// Per block: (head i, batch b, 32-token chunk c).
// GEMM2: F = relu(Y @ W1_i^T + b1)  [32 x 384, K=96], in two N-halves of 192
// GEMM3: A = F @ W2_i^T + b2        [32 x 96, K=384], accumulated over the halves
// LDS: Ys 6144B + Ws 36864B (W1-half then W2-half) + Fs 12288B = 55296B

__global__ __launch_bounds__(256) void mlp_logits(
    const unsigned short* __restrict__ Hi,
    const unsigned short* __restrict__ W1bf,  // (8*384) x 96
    const unsigned short* __restrict__ W2bf,  // (8*96) x 384
    const float* __restrict__ b1,             // 8*384
    const float* __restrict__ b2,             // 8*96
    unsigned short* __restrict__ Alog) {
  __shared__ __align__(16) unsigned short Ys[32 * 96];
  __shared__ __align__(16) unsigned short Ws[192 * 96];
  __shared__ __align__(16) unsigned short Fs[32 * 192];

  const int x = blockIdx.x;
  const int c = x & 15;
  const int b = (x >> 4) & 127;
  const int hd = x >> 11;  // head, slowest -> concurrent blocks share weights in L2

  const int tid = threadIdx.x;
  const int w = tid >> 6;
  const int lane = tid & 63;
  const int r = lane & 15;
  const int q = lane >> 4;

  const int mt = w & 1;          // m-tile (16 tokens) for both GEMMs
  const int nb2 = (w >> 1) * 6;  // GEMM2 n-tile base (of 12)
  const int nb3 = (w >> 1) * 3;  // GEMM3 n-tile base (of 6)

  // stage Y chunk: 32x96 bf16, contiguous in (i,b,s,h) layout = 384 16B chunks
  const unsigned short* ysrc = Hi + ((size_t)(hd * 128 + b) * 512 + c * 32) * 96;
  g2l16(ysrc + (size_t)(w * 64 + lane) * 8, &Ys[w * 512]);
  if (w < 2) g2l16(ysrc + (size_t)((4 + w) * 64 + lane) * 8, &Ys[(4 + w) * 512]);

  f32x4 acc3[3];
#pragma unroll
  for (int t = 0; t < 3; ++t) acc3[t] = (f32x4){0.f, 0.f, 0.f, 0.f};

  for (int ph = 0; ph < 2; ++ph) {
    __syncthreads();  // Ys ready (iter0) / Ws+Fs free (iter1)
    // W1 half: rows [ph*192, ph*192+192) x 96 -- contiguous 36864B = 2304 chunks
    const unsigned short* w1src = W1bf + (size_t)(hd * 384 + ph * 192) * 96;
#pragma unroll
    for (int j = 0; j < 9; ++j)
      g2l16(w1src + (size_t)((j * 4 + w) * 64 + lane) * 8, &Ws[(j * 4 + w) * 512]);
    __syncthreads();

    // GEMM2: M=32 N=192 K=96
    f32x4 acc2[6];
#pragma unroll
    for (int t = 0; t < 6; ++t) acc2[t] = (f32x4){0.f, 0.f, 0.f, 0.f};
#pragma unroll
    for (int ks = 0; ks < 3; ++ks) {
      bf16x8 a = *(const bf16x8*)&Ys[(mt * 16 + r) * 96 + ks * 32 + q * 8];
#pragma unroll
      for (int t = 0; t < 6; ++t) {
        bf16x8 bv = *(const bf16x8*)&Ws[((nb2 + t) * 16 + r) * 96 + ks * 32 + q * 8];
        acc2[t] = __builtin_amdgcn_mfma_f32_16x16x32_bf16(a, bv, acc2[t], 0, 0, 0);
      }
    }
    // epilogue: +b1, relu, -> Fs bf16 [s][f'] stride 192
#pragma unroll
    for (int t = 0; t < 6; ++t) {
      const int f = (nb2 + t) * 16 + r;
      const float bias = b1[hd * 384 + ph * 192 + f];
#pragma unroll
      for (int rg = 0; rg < 4; ++rg) {
        const int s = mt * 16 + q * 4 + rg;
        float v = acc2[t][rg] + bias;
        Fs[s * 192 + f] = f32_to_bf16(fmaxf(v, 0.f));
      }
    }
    __syncthreads();  // Fs complete; Ws (W1 half) no longer needed

    // W2 half: rows h=0..95, cols [ph*192, +192) of stride-384 rows
    const unsigned short* w2src = W2bf + (size_t)hd * 96 * 384 + ph * 192;
#pragma unroll
    for (int j = 0; j < 9; ++j) {
      const int cc = (j * 4 + w) * 64 + lane;  // 0..2303
      const int row = cc / 24;
      const int col = cc - row * 24;
      g2l16(w2src + (size_t)row * 384 + col * 8, &Ws[(j * 4 + w) * 512]);
    }
    __syncthreads();

    // GEMM3 partial: M=32 N=96 K=192 (accumulate across halves)
#pragma unroll
    for (int ks = 0; ks < 6; ++ks) {
      bf16x8 a = *(const bf16x8*)&Fs[(mt * 16 + r) * 192 + ks * 32 + q * 8];
#pragma unroll
      for (int t = 0; t < 3; ++t) {
        bf16x8 bv = *(const bf16x8*)&Ws[((nb3 + t) * 16 + r) * 192 + ks * 32 + q * 8];
        acc3[t] = __builtin_amdgcn_mfma_f32_16x16x32_bf16(a, bv, acc3[t], 0, 0, 0);
      }
    }
  }

  // final epilogue: +b2, store logits bf16 (i,b,s,h)
  unsigned short* aout = Alog + ((size_t)(hd * 128 + b) * 512 + c * 32) * 96;
#pragma unroll
  for (int t = 0; t < 3; ++t) {
    const int h = (nb3 + t) * 16 + r;
    const float bias = b2[hd * 96 + h];
#pragma unroll
    for (int rg = 0; rg < 4; ++rg) {
      const int s = mt * 16 + q * 4 + rg;
      aout[(size_t)s * 96 + h] = f32_to_bf16(acc3[t][rg] + bias);
    }
  }
}

// ---------------- kernel 3: masked softmax over S + weighted pool ----------------
// One block per (i,b); thread h (0..95) owns one output column.

__global__ __launch_bounds__(128) void softpool(
    const unsigned short* __restrict__ Hi,
    const unsigned short* __restrict__ Alog,
    const float* __restrict__ mask,  // B x S
    float* __restrict__ out) {       // B x 768
  __shared__ float msk[512];
  const int x = blockIdx.x;  // i*128 + b
  const int hd = x >> 7;
  const int b = x & 127;
  const int tid = threadIdx.x;
  for (int s = tid; s < 512; s += 128) msk[s] = mask[b * 512 + s];
  __syncthreads();
  if (tid >= 96) return;
  const int h = tid;
  const unsigned short* abase = Alog + (size_t)x * 512 * 96 + h;
  const unsigned short* hbase = Hi + (size_t)x * 512 * 96 + h;

  float m = -1e30f;
  for (int s = 0; s < 512; ++s) {
    if (msk[s] > 0.5f) m = fmaxf(m, bf16_to_f32(abase[(size_t)s * 96]));
  }
  float l = 0.f, v = 0.f;
  for (int s = 0; s < 512; ++s) {
    if (msk[s] > 0.5f) {
      float e = __expf(bf16_to_f32(abase[(size_t)s * 96]) - m);
      l += e;
      v += e * bf16_to_f32(hbase[(size_t)s * 96]);
    }
  }
  out[b * 768 + hd * 96 + h] = v / l;
}

// ---------------- launcher ----------------

extern "C" void kernel_launch(void* const* d_in, const int* in_sizes, int n_in,
                              void* d_out, int out_size, void* d_ws, size_t ws_size,
                              hipStream_t stream) {
  const float* X    = (const float*)d_in[0];
  const float* mask = (const float*)d_in[1];
  const float* P    = (const float*)d_in[2];
  const float* bP   = (const float*)d_in[3];
  const float* W1   = (const float*)d_in[4];
  const float* b1   = (const float*)d_in[5];
  const float* W2   = (const float*)d_in[6];
  const float* b2   = (const float*)d_in[7];
  float* out = (float*)d_out;
  (void)in_sizes; (void)n_in; (void)out_size; (void)ws_size;

  unsigned short* Xbf  = (unsigned short*)d_ws;
  unsigned short* Pbf  = Xbf + N_X;
  unsigned short* W1bf = Pbf + N_P;
  unsigned short* W2bf = W1bf + N_W1;
  unsigned short* Hi   = W2bf + N_W2;
  unsigned short* Alog = Hi + N_HI;
  // total ws use: (N_X + N_P + N_W1 + N_W2 + 2*N_HI) * 2 bytes ~= 304 MB

  cast_f32_bf16<<<N_X / 4 / 256, 256, 0, stream>>>(X, Xbf, N_X / 4);
  cast_f32_bf16<<<N_P / 4 / 256, 256, 0, stream>>>(P, Pbf, N_P / 4);
  cast_f32_bf16<<<N_W1 / 4 / 256, 256, 0, stream>>>(W1, W1bf, N_W1 / 4);
  cast_f32_bf16<<<N_W2 / 4 / 256, 256, 0, stream>>>(W2, W2bf, N_W2 / 4);

  gemm_hi<<<dim3(6, 512), 256, 0, stream>>>(Xbf, Pbf, bP, Hi);
  mlp_logits<<<8 * 128 * 16, 256, 0, stream>>>(Hi, W1bf, W2bf, b1, b2, Alog);
  softpool<<<8 * 128, 128, 0, stream>>>(Hi, Alog, mask, out);
}

// Round 2
// 680.618 us; speedup vs baseline: 1.4726x; 1.4726x over previous
//
#include <hip/hip_runtime.h>
#include <stdint.h>

// ---------------- common types / helpers ----------------

typedef short bf16x8 __attribute__((ext_vector_type(8)));
typedef float f32x4 __attribute__((ext_vector_type(4)));

struct alignas(8) us4 { unsigned short x, y, z, w; };

__device__ __forceinline__ unsigned short f32_to_bf16(float f) {
  union { float f; uint32_t u; } v; v.f = f;
  uint32_t u = v.u;
  uint32_t r = (u + 0x7fffu + ((u >> 16) & 1u)) >> 16;  // RNE
  return (unsigned short)r;
}

__device__ __forceinline__ float bf16_to_f32(unsigned short h) {
  union { uint32_t u; float f; } v; v.u = ((uint32_t)h) << 16;
  return v.f;
}

// async global->LDS, 16B per lane; LDS dest is wave-uniform base + lane*16
__device__ __forceinline__ void g2l16(const unsigned short* g, unsigned short* l) {
  __builtin_amdgcn_global_load_lds((__attribute__((address_space(1))) void*)g,
                                   (__attribute__((address_space(3))) void*)l,
                                   16, 0, 0);
}

// ---------------- problem constants ----------------
// B=128, S=512, D=768, NH=8, HD=96, HID=384

#define N_X   50331648   // 128*512*768
#define N_P   589824     // 8*96*768
#define N_W1  294912     // 8*384*96
#define N_W2  294912     // 8*96*384
#define N_HI  50331648   // 8*128*512*96

// ---------------- kernel 0: fp32 -> bf16 cast ----------------

__global__ __launch_bounds__(256) void cast_f32_bf16(
    const float* __restrict__ src, unsigned short* __restrict__ dst, int n4) {
  int idx = blockIdx.x * 256 + threadIdx.x;
  if (idx >= n4) return;
  float4 v = ((const float4*)src)[idx];
  us4 o;
  o.x = f32_to_bf16(v.x);
  o.y = f32_to_bf16(v.y);
  o.z = f32_to_bf16(v.z);
  o.w = f32_to_bf16(v.w);
  ((us4*)dst)[idx] = o;
}

// ---------------- kernel 1: Hi = X @ P^T + bP ----------------
// (unchanged from R0 — isolating the softpool rewrite)

__global__ __launch_bounds__(256) void gemm_hi(
    const unsigned short* __restrict__ Xbf,
    const unsigned short* __restrict__ Pbf,
    const float* __restrict__ bP,
    unsigned short* __restrict__ Hi) {
  __shared__ __align__(16) unsigned short As[128 * 32];
  __shared__ __align__(16) unsigned short Bs[128 * 32];

  const int tid = threadIdx.x;
  const int w = tid >> 6;
  const int lane = tid & 63;
  const int r = lane & 15;
  const int q = lane >> 4;
  const int bn = blockIdx.x;  // 0..5
  const int bm = blockIdx.y;  // 0..511
  const int wr = w >> 1, wc = w & 1;

  f32x4 acc[4][4];
#pragma unroll
  for (int a = 0; a < 4; ++a)
#pragma unroll
    for (int c = 0; c < 4; ++c) acc[a][c] = (f32x4){0.f, 0.f, 0.f, 0.f};

  const int ldr = lane >> 2;
  const int ldc = (lane & 3) * 8;
  const unsigned short* Abase = Xbf + (size_t)(bm * 128) * 768 + ldc;
  const unsigned short* Bbase = Pbf + (size_t)(bn * 128) * 768 + ldc;

  for (int k0 = 0; k0 < 768; k0 += 32) {
    __syncthreads();
    g2l16(Abase + (size_t)(w * 16 + ldr) * 768 + k0, &As[w * 512]);
    g2l16(Abase + (size_t)(64 + w * 16 + ldr) * 768 + k0, &As[(4 + w) * 512]);
    g2l16(Bbase + (size_t)(w * 16 + ldr) * 768 + k0, &Bs[w * 512]);
    g2l16(Bbase + (size_t)(64 + w * 16 + ldr) * 768 + k0, &Bs[(4 + w) * 512]);
    __syncthreads();

    bf16x8 af[4], bfr[4];
#pragma unroll
    for (int t = 0; t < 4; ++t)
      af[t] = *(const bf16x8*)&As[(wr * 64 + t * 16 + r) * 32 + q * 8];
#pragma unroll
    for (int t = 0; t < 4; ++t)
      bfr[t] = *(const bf16x8*)&Bs[(wc * 64 + t * 16 + r) * 32 + q * 8];
#pragma unroll
    for (int mt = 0; mt < 4; ++mt)
#pragma unroll
      for (int nt = 0; nt < 4; ++nt)
        acc[mt][nt] = __builtin_amdgcn_mfma_f32_16x16x32_bf16(
            af[mt], bfr[nt], acc[mt][nt], 0, 0, 0);
  }

  const int bb = bm >> 2;
  const int sb = (bm & 3) * 128 + wr * 64;
#pragma unroll
  for (int nt = 0; nt < 4; ++nt) {
    const int n0 = bn * 128 + wc * 64 + nt * 16;
    const int hd = n0 / 96;
    const int h = n0 - hd * 96 + r;
    const float bias = bP[n0 + r];
    unsigned short* obase = Hi + (size_t)(hd * 128 + bb) * 512 * 96 + h;
#pragma unroll
    for (int mt = 0; mt < 4; ++mt) {
#pragma unroll
      for (int rg = 0; rg < 4; ++rg) {
        const int s = sb + mt * 16 + q * 4 + rg;
        obase[(size_t)s * 96] = f32_to_bf16(acc[mt][nt][rg] + bias);
      }
    }
  }
}

// ---------------- kernel 2: fused per-head MLP -> logits ----------------
// (unchanged from R0)

__global__ __launch_bounds__(256) void mlp_logits(
    const unsigned short* __restrict__ Hi,
    const unsigned short* __restrict__ W1bf,
    const unsigned short* __restrict__ W2bf,
    const float* __restrict__ b1,
    const float* __restrict__ b2,
    unsigned short* __restrict__ Alog) {
  __shared__ __align__(16) unsigned short Ys[32 * 96];
  __shared__ __align__(16) unsigned short Ws[192 * 96];
  __shared__ __align__(16) unsigned short Fs[32 * 192];

  const int x = blockIdx.x;
  const int c = x & 15;
  const int b = (x >> 4) & 127;
  const int hd = x >> 11;

  const int tid = threadIdx.x;
  const int w = tid >> 6;
  const int lane = tid & 63;
  const int r = lane & 15;
  const int q = lane >> 4;

  const int mt = w & 1;
  const int nb2 = (w >> 1) * 6;
  const int nb3 = (w >> 1) * 3;

  const unsigned short* ysrc = Hi + ((size_t)(hd * 128 + b) * 512 + c * 32) * 96;
  g2l16(ysrc + (size_t)(w * 64 + lane) * 8, &Ys[w * 512]);
  if (w < 2) g2l16(ysrc + (size_t)((4 + w) * 64 + lane) * 8, &Ys[(4 + w) * 512]);

  f32x4 acc3[3];
#pragma unroll
  for (int t = 0; t < 3; ++t) acc3[t] = (f32x4){0.f, 0.f, 0.f, 0.f};

  for (int ph = 0; ph < 2; ++ph) {
    __syncthreads();
    const unsigned short* w1src = W1bf + (size_t)(hd * 384 + ph * 192) * 96;
#pragma unroll
    for (int j = 0; j < 9; ++j)
      g2l16(w1src + (size_t)((j * 4 + w) * 64 + lane) * 8, &Ws[(j * 4 + w) * 512]);
    __syncthreads();

    f32x4 acc2[6];
#pragma unroll
    for (int t = 0; t < 6; ++t) acc2[t] = (f32x4){0.f, 0.f, 0.f, 0.f};
#pragma unroll
    for (int ks = 0; ks < 3; ++ks) {
      bf16x8 a = *(const bf16x8*)&Ys[(mt * 16 + r) * 96 + ks * 32 + q * 8];
#pragma unroll
      for (int t = 0; t < 6; ++t) {
        bf16x8 bv = *(const bf16x8*)&Ws[((nb2 + t) * 16 + r) * 96 + ks * 32 + q * 8];
        acc2[t] = __builtin_amdgcn_mfma_f32_16x16x32_bf16(a, bv, acc2[t], 0, 0, 0);
      }
    }
#pragma unroll
    for (int t = 0; t < 6; ++t) {
      const int f = (nb2 + t) * 16 + r;
      const float bias = b1[hd * 384 + ph * 192 + f];
#pragma unroll
      for (int rg = 0; rg < 4; ++rg) {
        const int s = mt * 16 + q * 4 + rg;
        float v = acc2[t][rg] + bias;
        Fs[s * 192 + f] = f32_to_bf16(fmaxf(v, 0.f));
      }
    }
    __syncthreads();

    const unsigned short* w2src = W2bf + (size_t)hd * 96 * 384 + ph * 192;
#pragma unroll
    for (int j = 0; j < 9; ++j) {
      const int cc = (j * 4 + w) * 64 + lane;
      const int row = cc / 24;
      const int col = cc - row * 24;
      g2l16(w2src + (size_t)row * 384 + col * 8, &Ws[(j * 4 + w) * 512]);
    }
    __syncthreads();

#pragma unroll
    for (int ks = 0; ks < 6; ++ks) {
      bf16x8 a = *(const bf16x8*)&Fs[(mt * 16 + r) * 192 + ks * 32 + q * 8];
#pragma unroll
      for (int t = 0; t < 3; ++t) {
        bf16x8 bv = *(const bf16x8*)&Ws[((nb3 + t) * 16 + r) * 192 + ks * 32 + q * 8];
        acc3[t] = __builtin_amdgcn_mfma_f32_16x16x32_bf16(a, bv, acc3[t], 0, 0, 0);
      }
    }
  }

  unsigned short* aout = Alog + ((size_t)(hd * 128 + b) * 512 + c * 32) * 96;
#pragma unroll
  for (int t = 0; t < 3; ++t) {
    const int h = (nb3 + t) * 16 + r;
    const float bias = b2[hd * 96 + h];
#pragma unroll
    for (int rg = 0; rg < 4; ++rg) {
      const int s = mt * 16 + q * 4 + rg;
      aout[(size_t)s * 96 + h] = f32_to_bf16(acc3[t][rg] + bias);
    }
  }
}

// ---------------- kernel 3: masked softmax over S + weighted pool (v2) ----------------
// One block per (i,b). 384 threads = 32 s-groups x 12 h-lanes; each thread owns
// 8 consecutive h (one bf16x8 per row) and 16 s rows. Branch-free mask via
// additive bias (exp(-1e30 - m) == 0). Partials merged through LDS.

__global__ __launch_bounds__(384) void softpool(
    const unsigned short* __restrict__ Hi,
    const unsigned short* __restrict__ Alog,
    const float* __restrict__ mask,  // B x S
    float* __restrict__ out) {       // B x 768
  __shared__ float bias[512];
  __shared__ float redl[32][96];
  __shared__ float redv[32][96];
  __shared__ float mfin[96];

  const int x = blockIdx.x;  // i*128 + b
  const int hd = x >> 7;
  const int b = x & 127;
  const int tid = threadIdx.x;
  const int g = tid / 12;        // s-group 0..31 (16 rows each)
  const int t12 = tid - g * 12;  // 0..11
  const int h8 = t12 * 8;        // owns h in [h8, h8+8)

  for (int s = tid; s < 512; s += 384)
    bias[s] = mask[b * 512 + s] > 0.5f ? 0.f : -1e30f;
  __syncthreads();

  const unsigned short* abase = Alog + (size_t)x * 512 * 96;
  const unsigned short* hbase = Hi + (size_t)x * 512 * 96;

  // pass A: per-group max (branch-free, fully unrolled -> 16 loads in flight)
  float m[8];
#pragma unroll
  for (int j = 0; j < 8; ++j) m[j] = -3e30f;
#pragma unroll
  for (int it = 0; it < 16; ++it) {
    const int s = g * 16 + it;
    bf16x8 a = *(const bf16x8*)&abase[(size_t)s * 96 + h8];
    const float bs = bias[s];
#pragma unroll
    for (int j = 0; j < 8; ++j)
      m[j] = fmaxf(m[j], bf16_to_f32((unsigned short)a[j]) + bs);
  }
#pragma unroll
  for (int j = 0; j < 8; ++j) redl[g][h8 + j] = m[j];
  __syncthreads();
  if (tid < 96) {
    float mm = -3e30f;
#pragma unroll
    for (int gg = 0; gg < 32; ++gg) mm = fmaxf(mm, redl[gg][tid]);
    mfin[tid] = mm;
  }
  __syncthreads();
  float mf[8];
#pragma unroll
  for (int j = 0; j < 8; ++j) mf[j] = mfin[h8 + j];
  __syncthreads();  // redl about to be overwritten

  // pass B: exp-sum and weighted Hi sum
  float l[8], v[8];
#pragma unroll
  for (int j = 0; j < 8; ++j) { l[j] = 0.f; v[j] = 0.f; }
#pragma unroll
  for (int it = 0; it < 16; ++it) {
    const int s = g * 16 + it;
    bf16x8 a = *(const bf16x8*)&abase[(size_t)s * 96 + h8];
    bf16x8 hv = *(const bf16x8*)&hbase[(size_t)s * 96 + h8];
    const float bs = bias[s];
#pragma unroll
    for (int j = 0; j < 8; ++j) {
      float e = __expf(bf16_to_f32((unsigned short)a[j]) + bs - mf[j]);
      l[j] += e;
      v[j] += e * bf16_to_f32((unsigned short)hv[j]);
    }
  }
#pragma unroll
  for (int j = 0; j < 8; ++j) {
    redl[g][h8 + j] = l[j];
    redv[g][h8 + j] = v[j];
  }
  __syncthreads();
  if (tid < 96) {
    float ls = 0.f, vs = 0.f;
#pragma unroll
    for (int gg = 0; gg < 32; ++gg) { ls += redl[gg][tid]; vs += redv[gg][tid]; }
    out[b * 768 + hd * 96 + tid] = vs / ls;
  }
}

// ---------------- launcher ----------------

extern "C" void kernel_launch(void* const* d_in, const int* in_sizes, int n_in,
                              void* d_out, int out_size, void* d_ws, size_t ws_size,
                              hipStream_t stream) {
  const float* X    = (const float*)d_in[0];
  const float* mask = (const float*)d_in[1];
  const float* P    = (const float*)d_in[2];
  const float* bP   = (const float*)d_in[3];
  const float* W1   = (const float*)d_in[4];
  const float* b1   = (const float*)d_in[5];
  const float* W2   = (const float*)d_in[6];
  const float* b2   = (const float*)d_in[7];
  float* out = (float*)d_out;
  (void)in_sizes; (void)n_in; (void)out_size; (void)ws_size;

  unsigned short* Xbf  = (unsigned short*)d_ws;
  unsigned short* Pbf  = Xbf + N_X;
  unsigned short* W1bf = Pbf + N_P;
  unsigned short* W2bf = W1bf + N_W1;
  unsigned short* Hi   = W2bf + N_W2;
  unsigned short* Alog = Hi + N_HI;

  cast_f32_bf16<<<N_X / 4 / 256, 256, 0, stream>>>(X, Xbf, N_X / 4);
  cast_f32_bf16<<<N_P / 4 / 256, 256, 0, stream>>>(P, Pbf, N_P / 4);
  cast_f32_bf16<<<N_W1 / 4 / 256, 256, 0, stream>>>(W1, W1bf, N_W1 / 4);
  cast_f32_bf16<<<N_W2 / 4 / 256, 256, 0, stream>>>(W2, W2bf, N_W2 / 4);

  gemm_hi<<<dim3(6, 512), 256, 0, stream>>>(Xbf, Pbf, bP, Hi);
  mlp_logits<<<8 * 128 * 16, 256, 0, stream>>>(Hi, W1bf, W2bf, b1, b2, Alog);
  softpool<<<8 * 128, 384, 0, stream>>>(Hi, Alog, mask, out);
}

// Round 3
// 580.981 us; speedup vs baseline: 1.7251x; 1.1715x over previous
//
#include <hip/hip_runtime.h>
#include <stdint.h>

// ---------------- common types / helpers ----------------

typedef short bf16x8 __attribute__((ext_vector_type(8)));
typedef float f32x4 __attribute__((ext_vector_type(4)));

struct alignas(8) us4 { unsigned short x, y, z, w; };

__device__ __forceinline__ unsigned short f32_to_bf16(float f) {
  union { float f; uint32_t u; } v; v.f = f;
  uint32_t u = v.u;
  uint32_t r = (u + 0x7fffu + ((u >> 16) & 1u)) >> 16;  // RNE
  return (unsigned short)r;
}

__device__ __forceinline__ float bf16_to_f32(unsigned short h) {
  union { uint32_t u; float f; } v; v.u = ((uint32_t)h) << 16;
  return v.f;
}

// pack two f32 into bf16x2 by truncation: one v_perm_b32
__device__ __forceinline__ uint32_t pack_bf16_trunc(float lo, float hi) {
  union { float f; uint32_t u; } a, b; a.f = lo; b.f = hi;
  return __builtin_amdgcn_perm(b.u, a.u, 0x07060302u);  // [lo.hi16, hi.hi16]
}

// async global->LDS, 16B per lane; LDS dest is wave-uniform base + lane*16
__device__ __forceinline__ void g2l16(const unsigned short* g, unsigned short* l) {
  __builtin_amdgcn_global_load_lds((__attribute__((address_space(1))) void*)g,
                                   (__attribute__((address_space(3))) void*)l,
                                   16, 0, 0);
}

// ---------------- problem constants ----------------
// B=128, S=512, D=768, NH=8, HD=96, HID=384

#define N_X   50331648   // 128*512*768
#define N_P   589824     // 8*96*768
#define N_W1  294912     // 8*384*96
#define N_W2  294912     // 8*96*384
#define N_HI  50331648   // 8*128*512*96

// ---------------- kernel 0: fp32 -> bf16 cast ----------------

__global__ __launch_bounds__(256) void cast_f32_bf16(
    const float* __restrict__ src, unsigned short* __restrict__ dst, int n4) {
  int idx = blockIdx.x * 256 + threadIdx.x;
  if (idx >= n4) return;
  float4 v = ((const float4*)src)[idx];
  us4 o;
  o.x = f32_to_bf16(v.x);
  o.y = f32_to_bf16(v.y);
  o.z = f32_to_bf16(v.z);
  o.w = f32_to_bf16(v.w);
  ((us4*)dst)[idx] = o;
}

// ---------------- kernel 1: Hi = X @ P^T + bP ----------------
// (unchanged — isolating the mlp_logits rewrite)

__global__ __launch_bounds__(256) void gemm_hi(
    const unsigned short* __restrict__ Xbf,
    const unsigned short* __restrict__ Pbf,
    const float* __restrict__ bP,
    unsigned short* __restrict__ Hi) {
  __shared__ __align__(16) unsigned short As[128 * 32];
  __shared__ __align__(16) unsigned short Bs[128 * 32];

  const int tid = threadIdx.x;
  const int w = tid >> 6;
  const int lane = tid & 63;
  const int r = lane & 15;
  const int q = lane >> 4;
  const int bn = blockIdx.x;  // 0..5
  const int bm = blockIdx.y;  // 0..511
  const int wr = w >> 1, wc = w & 1;

  f32x4 acc[4][4];
#pragma unroll
  for (int a = 0; a < 4; ++a)
#pragma unroll
    for (int c = 0; c < 4; ++c) acc[a][c] = (f32x4){0.f, 0.f, 0.f, 0.f};

  const int ldr = lane >> 2;
  const int ldc = (lane & 3) * 8;
  const unsigned short* Abase = Xbf + (size_t)(bm * 128) * 768 + ldc;
  const unsigned short* Bbase = Pbf + (size_t)(bn * 128) * 768 + ldc;

  for (int k0 = 0; k0 < 768; k0 += 32) {
    __syncthreads();
    g2l16(Abase + (size_t)(w * 16 + ldr) * 768 + k0, &As[w * 512]);
    g2l16(Abase + (size_t)(64 + w * 16 + ldr) * 768 + k0, &As[(4 + w) * 512]);
    g2l16(Bbase + (size_t)(w * 16 + ldr) * 768 + k0, &Bs[w * 512]);
    g2l16(Bbase + (size_t)(64 + w * 16 + ldr) * 768 + k0, &Bs[(4 + w) * 512]);
    __syncthreads();

    bf16x8 af[4], bfr[4];
#pragma unroll
    for (int t = 0; t < 4; ++t)
      af[t] = *(const bf16x8*)&As[(wr * 64 + t * 16 + r) * 32 + q * 8];
#pragma unroll
    for (int t = 0; t < 4; ++t)
      bfr[t] = *(const bf16x8*)&Bs[(wc * 64 + t * 16 + r) * 32 + q * 8];
#pragma unroll
    for (int mt = 0; mt < 4; ++mt)
#pragma unroll
      for (int nt = 0; nt < 4; ++nt)
        acc[mt][nt] = __builtin_amdgcn_mfma_f32_16x16x32_bf16(
            af[mt], bfr[nt], acc[mt][nt], 0, 0, 0);
  }

  const int bb = bm >> 2;
  const int sb = (bm & 3) * 128 + wr * 64;
#pragma unroll
  for (int nt = 0; nt < 4; ++nt) {
    const int n0 = bn * 128 + wc * 64 + nt * 16;
    const int hd = n0 / 96;
    const int h = n0 - hd * 96 + r;
    const float bias = bP[n0 + r];
    unsigned short* obase = Hi + (size_t)(hd * 128 + bb) * 512 * 96 + h;
#pragma unroll
    for (int mt = 0; mt < 4; ++mt) {
#pragma unroll
      for (int rg = 0; rg < 4; ++rg) {
        const int s = sb + mt * 16 + q * 4 + rg;
        obase[(size_t)s * 96] = f32_to_bf16(acc[mt][nt][rg] + bias);
      }
    }
  }
}

// ---------------- kernel 2: fused per-head MLP -> logits (v2) ----------------
// Block = (head, batch, 128-token chunk); grid 8*128*4 = 4096, 256 thr = 4 waves.
// 4 phases over 96-wide quarters of HID:
//   GEMM2 computes F^T = W1q @ Y^T (M=f,N=s,K=96) so consecutive f sit in
//   consecutive acc regs -> epilogue packs bf16 pairs (v_perm) + ds_write_b64.
//   Fs row stride 104 shorts (52 words == 20 mod 32) -> spread bank starts.
//   W2q staged via per-lane gather g2l16 into K-chunked [kb][h][32] tiles ->
//   b-frag reads use the measured-OK gemm_hi bank pattern.
//   GEMM3 (M=s,N=h,K=f) accumulates across phases in regs.
// LDS ~70 KB -> 2 blocks/CU.

__global__ __launch_bounds__(256, 2) void mlp_logits(
    const unsigned short* __restrict__ Hi,
    const unsigned short* __restrict__ W1bf,  // (8*384) x 96
    const unsigned short* __restrict__ W2bf,  // (8*96) x 384
    const float* __restrict__ b1,             // 8*384
    const float* __restrict__ b2,             // 8*96
    unsigned short* __restrict__ Alog) {
  __shared__ __align__(16) unsigned short Ys[128 * 96];   // [s][96]
  __shared__ __align__(16) unsigned short Ws[96 * 96];    // W1q:[f][96] / W2q:[kb][h][32]
  __shared__ __align__(16) unsigned short Fs[128 * 104];  // [s][96 + 8 pad]
  __shared__ __align__(16) float b1s[384];
  __shared__ __align__(16) float b2s[96];

  const int x = blockIdx.x;
  const int c = x & 3;             // token chunk (128)
  const int b = (x >> 2) & 127;    // batch
  const int hd = x >> 9;           // head (slowest -> weight L2 sharing)

  const int tid = threadIdx.x;
  const int w = tid >> 6;
  const int lane = tid & 63;
  const int r = lane & 15;
  const int q = lane >> 4;

  // stage Y chunk: 128x96 bf16 = 1536 16B-chunks, contiguous in Hi
  const unsigned short* ysrc = Hi + ((size_t)(hd * 128 + b) * 512 + c * 128) * 96;
#pragma unroll
  for (int it = 0; it < 6; ++it)
    g2l16(ysrc + (size_t)((it * 4 + w) * 64 + lane) * 8, &Ys[(it * 4 + w) * 512]);

  if (tid < 96) b2s[tid] = b2[hd * 96 + tid];
  for (int i = tid; i < 384; i += 256) b1s[i] = b1[hd * 384 + i];

  f32x4 acc3[2][6];
#pragma unroll
  for (int sp = 0; sp < 2; ++sp)
#pragma unroll
    for (int nt = 0; nt < 6; ++nt) acc3[sp][nt] = (f32x4){0.f, 0.f, 0.f, 0.f};

  for (int ph = 0; ph < 4; ++ph) {
    __syncthreads();  // Ws/Fs free (prev GEMM3 done); iter0: no-op ordering
    // stage W1 quarter: rows f = ph*96..+95, contiguous 96*96 shorts = 1152 chunks
    const unsigned short* w1src = W1bf + ((size_t)hd * 384 + ph * 96) * 96;
#pragma unroll
    for (int it = 0; it < 4; ++it)
      g2l16(w1src + (size_t)((it * 4 + w) * 64 + lane) * 8, &Ws[(it * 4 + w) * 512]);
    if (w < 2)
      g2l16(w1src + (size_t)((16 + w) * 64 + lane) * 8, &Ws[(16 + w) * 512]);
    __syncthreads();  // Ws ready (also waits Ys on iter0)

    // GEMM2: F^T = W1q @ Y^T. M=96(f), N=128(s), K=96. Wave: all 6 f-tiles x 2 s-tiles.
    f32x4 acc2[6][2];
#pragma unroll
    for (int ft = 0; ft < 6; ++ft)
#pragma unroll
      for (int sp = 0; sp < 2; ++sp) acc2[ft][sp] = (f32x4){0.f, 0.f, 0.f, 0.f};
#pragma unroll
    for (int kb = 0; kb < 3; ++kb) {
      bf16x8 bfrg[2];
#pragma unroll
      for (int sp = 0; sp < 2; ++sp)
        bfrg[sp] = *(const bf16x8*)&Ys[((w * 2 + sp) * 16 + r) * 96 + kb * 32 + q * 8];
#pragma unroll
      for (int ft = 0; ft < 6; ++ft) {
        bf16x8 afrg = *(const bf16x8*)&Ws[(ft * 16 + r) * 96 + kb * 32 + q * 8];
#pragma unroll
        for (int sp = 0; sp < 2; ++sp)
          acc2[ft][sp] = __builtin_amdgcn_mfma_f32_16x16x32_bf16(
              afrg, bfrg[sp], acc2[ft][sp], 0, 0, 0);
      }
    }
    // epilogue: +b1, relu, pack pairs, b64 write to Fs
    // C-layout: col(lane&15)=s, row(q*4+rg)=f -> f consecutive in regs
#pragma unroll
    for (int ft = 0; ft < 6; ++ft) {
      float4 bv = *(const float4*)&b1s[ph * 96 + ft * 16 + q * 4];
#pragma unroll
      for (int sp = 0; sp < 2; ++sp) {
        const int s = (w * 2 + sp) * 16 + r;
        float v0 = fmaxf(acc2[ft][sp][0] + bv.x, 0.f);
        float v1 = fmaxf(acc2[ft][sp][1] + bv.y, 0.f);
        float v2 = fmaxf(acc2[ft][sp][2] + bv.z, 0.f);
        float v3 = fmaxf(acc2[ft][sp][3] + bv.w, 0.f);
        uint2 pk;
        pk.x = pack_bf16_trunc(v0, v1);
        pk.y = pack_bf16_trunc(v2, v3);
        *(uint2*)((uint32_t*)&Fs[0] + s * 52 + ft * 8 + q * 2) = pk;
      }
    }
    __syncthreads();  // Fs ready; Ws (W1q) consumed

    // stage W2 quarter: cols ph*96..+95 of 96 stride-384 rows, K-chunked [kb][h][32]
    const unsigned short* w2src = W2bf + (size_t)hd * 96 * 384 + ph * 96;
#pragma unroll
    for (int it = 0; it < 4; ++it) {
      const int ch = (it * 4 + w) * 64 + lane;  // 0..1023
      const int kb = ch / 384;
      const int rem = ch - kb * 384;
      g2l16(w2src + (size_t)(rem >> 2) * 384 + kb * 32 + (rem & 3) * 8,
            &Ws[(it * 4 + w) * 512]);
    }
    if (w < 2) {
      const int ch = (16 + w) * 64 + lane;  // 1024..1151
      const int kb = ch / 384;
      const int rem = ch - kb * 384;
      g2l16(w2src + (size_t)(rem >> 2) * 384 + kb * 32 + (rem & 3) * 8,
            &Ws[(16 + w) * 512]);
    }
    __syncthreads();  // Ws(W2q) ready

    // GEMM3 partial: M=128(s), N=96(h), K=96 this phase. Wave: 2 s-tiles x 6 h-tiles.
#pragma unroll
    for (int kb = 0; kb < 3; ++kb) {
      bf16x8 afrg[2];
#pragma unroll
      for (int sp = 0; sp < 2; ++sp)
        afrg[sp] = *(const bf16x8*)&Fs[((w * 2 + sp) * 16 + r) * 104 + kb * 32 + q * 8];
#pragma unroll
      for (int nt = 0; nt < 6; ++nt) {
        bf16x8 bfrg = *(const bf16x8*)&Ws[(kb * 96 + nt * 16 + r) * 32 + q * 8];
#pragma unroll
        for (int sp = 0; sp < 2; ++sp)
          acc3[sp][nt] = __builtin_amdgcn_mfma_f32_16x16x32_bf16(
              afrg[sp], bfrg, acc3[sp][nt], 0, 0, 0);
      }
    }
  }

  // final epilogue: +b2, store logits bf16 (i,b,s,h)
  unsigned short* aout = Alog + ((size_t)(hd * 128 + b) * 512 + c * 128) * 96;
#pragma unroll
  for (int nt = 0; nt < 6; ++nt) {
    const int h = nt * 16 + r;
    const float bias = b2s[h];
#pragma unroll
    for (int sp = 0; sp < 2; ++sp) {
#pragma unroll
      for (int rg = 0; rg < 4; ++rg) {
        const int s = (w * 2 + sp) * 16 + q * 4 + rg;
        aout[(size_t)s * 96 + h] = f32_to_bf16(acc3[sp][nt][rg] + bias);
      }
    }
  }
}

// ---------------- kernel 3: masked softmax over S + weighted pool ----------------
// (unchanged from R1)

__global__ __launch_bounds__(384) void softpool(
    const unsigned short* __restrict__ Hi,
    const unsigned short* __restrict__ Alog,
    const float* __restrict__ mask,  // B x S
    float* __restrict__ out) {       // B x 768
  __shared__ float bias[512];
  __shared__ float redl[32][96];
  __shared__ float redv[32][96];
  __shared__ float mfin[96];

  const int x = blockIdx.x;  // i*128 + b
  const int hd = x >> 7;
  const int b = x & 127;
  const int tid = threadIdx.x;
  const int g = tid / 12;
  const int t12 = tid - g * 12;
  const int h8 = t12 * 8;

  for (int s = tid; s < 512; s += 384)
    bias[s] = mask[b * 512 + s] > 0.5f ? 0.f : -1e30f;
  __syncthreads();

  const unsigned short* abase = Alog + (size_t)x * 512 * 96;
  const unsigned short* hbase = Hi + (size_t)x * 512 * 96;

  float m[8];
#pragma unroll
  for (int j = 0; j < 8; ++j) m[j] = -3e30f;
#pragma unroll
  for (int it = 0; it < 16; ++it) {
    const int s = g * 16 + it;
    bf16x8 a = *(const bf16x8*)&abase[(size_t)s * 96 + h8];
    const float bs = bias[s];
#pragma unroll
    for (int j = 0; j < 8; ++j)
      m[j] = fmaxf(m[j], bf16_to_f32((unsigned short)a[j]) + bs);
  }
#pragma unroll
  for (int j = 0; j < 8; ++j) redl[g][h8 + j] = m[j];
  __syncthreads();
  if (tid < 96) {
    float mm = -3e30f;
#pragma unroll
    for (int gg = 0; gg < 32; ++gg) mm = fmaxf(mm, redl[gg][tid]);
    mfin[tid] = mm;
  }
  __syncthreads();
  float mf[8];
#pragma unroll
  for (int j = 0; j < 8; ++j) mf[j] = mfin[h8 + j];
  __syncthreads();

  float l[8], v[8];
#pragma unroll
  for (int j = 0; j < 8; ++j) { l[j] = 0.f; v[j] = 0.f; }
#pragma unroll
  for (int it = 0; it < 16; ++it) {
    const int s = g * 16 + it;
    bf16x8 a = *(const bf16x8*)&abase[(size_t)s * 96 + h8];
    bf16x8 hv = *(const bf16x8*)&hbase[(size_t)s * 96 + h8];
    const float bs = bias[s];
#pragma unroll
    for (int j = 0; j < 8; ++j) {
      float e = __expf(bf16_to_f32((unsigned short)a[j]) + bs - mf[j]);
      l[j] += e;
      v[j] += e * bf16_to_f32((unsigned short)hv[j]);
    }
  }
#pragma unroll
  for (int j = 0; j < 8; ++j) {
    redl[g][h8 + j] = l[j];
    redv[g][h8 + j] = v[j];
  }
  __syncthreads();
  if (tid < 96) {
    float ls = 0.f, vs = 0.f;
#pragma unroll
    for (int gg = 0; gg < 32; ++gg) { ls += redl[gg][tid]; vs += redv[gg][tid]; }
    out[b * 768 + hd * 96 + tid] = vs / ls;
  }
}

// ---------------- launcher ----------------

extern "C" void kernel_launch(void* const* d_in, const int* in_sizes, int n_in,
                              void* d_out, int out_size, void* d_ws, size_t ws_size,
                              hipStream_t stream) {
  const float* X    = (const float*)d_in[0];
  const float* mask = (const float*)d_in[1];
  const float* P    = (const float*)d_in[2];
  const float* bP   = (const float*)d_in[3];
  const float* W1   = (const float*)d_in[4];
  const float* b1   = (const float*)d_in[5];
  const float* W2   = (const float*)d_in[6];
  const float* b2   = (const float*)d_in[7];
  float* out = (float*)d_out;
  (void)in_sizes; (void)n_in; (void)out_size; (void)ws_size;

  unsigned short* Xbf  = (unsigned short*)d_ws;
  unsigned short* Pbf  = Xbf + N_X;
  unsigned short* W1bf = Pbf + N_P;
  unsigned short* W2bf = W1bf + N_W1;
  unsigned short* Hi   = W2bf + N_W2;
  unsigned short* Alog = Hi + N_HI;

  cast_f32_bf16<<<N_X / 4 / 256, 256, 0, stream>>>(X, Xbf, N_X / 4);
  cast_f32_bf16<<<N_P / 4 / 256, 256, 0, stream>>>(P, Pbf, N_P / 4);
  cast_f32_bf16<<<N_W1 / 4 / 256, 256, 0, stream>>>(W1, W1bf, N_W1 / 4);
  cast_f32_bf16<<<N_W2 / 4 / 256, 256, 0, stream>>>(W2, W2bf, N_W2 / 4);

  gemm_hi<<<dim3(6, 512), 256, 0, stream>>>(Xbf, Pbf, bP, Hi);
  mlp_logits<<<8 * 128 * 4, 256, 0, stream>>>(Hi, W1bf, W2bf, b1, b2, Alog);
  softpool<<<8 * 128, 384, 0, stream>>>(Hi, Alog, mask, out);
}